// Round 4
// baseline (130.888 us; speedup 1.0000x reference)
//
#include <hip/hip_runtime.h>
#include <math.h>

// Problem constants
#define K_CODES 1024
#define C_DIM   128
#define HW      4096          // 64*64
#define CHW     (C_DIM*HW)    // per-batch stride in x
#define N_POS   65536         // 16*64*64
#define Q_ELEMS 8388608       // 16*128*64*64

// ws layout (byte offsets). Total < 272 KB (proven safe rounds 1-6).
#define WS_S    0             // float: sum of sqrt(d2min)
#define WS_C2   256           // float[1024]: ||c_k||^2
#define WS_IDX  8192          // int[65536]: final argmin index per position

// d_out scratch (overwritten by write_q later; stream-ordered, safe):
//   offset 0: bf16 codebook, LINEAR layout: row k at k*256B, channel c at
//   byte 2c. (R10: swizzle dropped -- A-frags now read straight from global,
//   no LDS, no bank conflicts.)

typedef __attribute__((ext_vector_type(8))) short short8;   // 8 bf16 (4 VGPRs)
typedef __attribute__((ext_vector_type(4))) float f32x4;    // MFMA acc

__device__ __forceinline__ unsigned short f2bf(float f) {   // fp32 -> bf16 RNE
    unsigned u = __float_as_uint(f);
    u += 0x7FFFu + ((u >> 16) & 1u);
    return (unsigned short)(u >> 16);
}

// ---------------------------------------------------------------------------
// Kernel 1: prep. Block k (64 lanes): row norm (same math as rounds 1-6),
// bf16 conversion into LINEAR global layout, S zeroing.
// ---------------------------------------------------------------------------
__global__ void prep_kernel(const float* __restrict__ cb, float* __restrict__ ws,
                            unsigned short* __restrict__ cbbf) {
    __shared__ __align__(16) unsigned short srow[128];
    int k = blockIdx.x;
    int l = threadIdx.x;                       // 64 lanes = 1 wave
    if (k == 0 && l == 0) *(float*)((char*)ws + WS_S) = 0.f;
    float v1 = cb[k * C_DIM + l];
    float v2 = cb[k * C_DIM + 64 + l];
    srow[l]      = f2bf(v1);
    srow[64 + l] = f2bf(v2);
    float ss = v1 * v1 + v2 * v2;
    #pragma unroll
    for (int off = 32; off > 0; off >>= 1) ss += __shfl_down(ss, off);
    if (l == 0) ((float*)((char*)ws + WS_C2))[k] = ss;
    __syncthreads();
    if (l < 16) ((uint4*)cbbf)[k * 16 + l] = ((const uint4*)srow)[l];
}

// ---------------------------------------------------------------------------
// Kernel 2: fused VQ. R10 restructure: NO LDS, NO BARRIERS, NO STAGING.
// 512 blocks x 256 thr (4 waves). Each wave owns 32 positions (16 lp x 2 pt)
// and scans all 1024 codes; A-fragments are loaded DIRECTLY FROM GLOBAL
// (cbbf linear): for fixed (cs,ct) the 64 lanes read 16 rows x 64 B fully-
// consumed lines (1 KB/instr) of the 256 KB L2-resident codebook. Waves are
// fully independent end-to-end -> VMEM/MFMA/VALU overlap via natural
// destaggering instead of barrier-lockstep phase serialization (the R6-R9
// wall). Occupancy VGPR-limited only: launch_bounds(256,3) -> <=170 VGPR.
// Math bit-identical to R6-R9: packed-score total order is strict (idx in
// low bits), so top-3 is scan-order-independent; same chains/butterfly/
// rescore/tie-break; same 32-position-per-atomic partition + trees.
// ---------------------------------------------------------------------------
__global__ __launch_bounds__(256, 3) void vq_mfma(const float* __restrict__ x,
                                                  const float* __restrict__ cb,
                                                  const unsigned short* __restrict__ cbbf,
                                                  const float* __restrict__ c2w,
                                                  int* __restrict__ idxw,
                                                  float* __restrict__ Sw) {
    const int t  = threadIdx.x;
    const int w  = t >> 6;                      // wave 0..3
    const int ln = t & 63;
    const int lp = ln & 15;                     // position lane (n index)
    const int q  = ln >> 4;                     // quad 0..3 (k sub-range)
    const int bid = blockIdx.x;                 // 512 blocks
    const int b   = bid >> 5;                   // batch
    const int s0  = ((bid & 31) << 7) + (w << 5);  // wave's 32-position start

    // ---- x: bf16 B-frags (2 pos-tiles) + per-position norms ----
    short8 xf[2][4];
    float  r2v[2];
    {
        float ss[2] = {0.f, 0.f};
        #pragma unroll
        for (int pt = 0; pt < 2; ++pt) {
            const float* xgp = x + b * CHW + s0 + pt * 16 + lp;
            #pragma unroll
            for (int cs = 0; cs < 4; ++cs) {
                union { short8 v; unsigned short u[8]; } fu;
                #pragma unroll
                for (int j = 0; j < 8; ++j) {
                    float vv = xgp[(32 * cs + 8 * q + j) * HW];
                    ss[pt] = fmaf(vv, vv, ss[pt]);
                    fu.u[j] = f2bf(vv);
                }
                xf[pt][cs] = fu.v;
            }
        }
        #pragma unroll
        for (int pt = 0; pt < 2; ++pt) {
            float s = ss[pt];
            s += __shfl_xor(s, 16);
            s += __shfl_xor(s, 32);
            r2v[pt] = -2.0f / fmaxf(sqrtf(s), 1e-12f);  // F.normalize eps
        }
    }

    const float FMAX = __uint_as_float(0x7F7FFFFFu);
    float m1[2] = {FMAX, FMAX}, m2[2] = {FMAX, FMAX}, m3[2] = {FMAX, FMAX};

    for (int i = 0; i < 16; ++i) {               // 16 chunks x 64 codes
        const int k0 = i << 6;

        f32x4 acc[4][2];
        #pragma unroll
        for (int ct = 0; ct < 4; ++ct)
            #pragma unroll
            for (int pt = 0; pt < 2; ++pt) acc[ct][pt] = 0;

        #pragma unroll
        for (int cs = 0; cs < 4; ++cs) {
            short8 ah[4];
            #pragma unroll
            for (int ct = 0; ct < 4; ++ct) {     // A[m=16ct+lp][k=32cs+8q+j]
                const unsigned short* ap =
                    cbbf + (k0 + 16 * ct + lp) * C_DIM + 32 * cs + 8 * q;
                ah[ct] = *(const short8*)ap;     // 16B, 16-aligned, L2-hot
            }
            #pragma unroll
            for (int ct = 0; ct < 4; ++ct)
                #pragma unroll
                for (int pt = 0; pt < 2; ++pt)
                    acc[ct][pt] = __builtin_amdgcn_mfma_f32_16x16x32_bf16(
                        ah[ct], xf[pt][cs], acc[ct][pt], 0, 0, 0);
        }

        // ---- epilogue: 32 scores, ~5 VALU each (fmaf, and_or, 2 med3, min) --
        #pragma unroll
        for (int ct = 0; ct < 4; ++ct) {
            float4 c2vv = *(const float4*)(c2w + k0 + 16 * ct + 4 * q);
            float c2a[4] = {c2vv.x, c2vv.y, c2vv.z, c2vv.w};
            const int kb0 = k0 + 16 * ct + 4 * q;
            #pragma unroll
            for (int pt = 0; pt < 2; ++pt) {
                #pragma unroll
                for (int reg = 0; reg < 4; ++reg) {
                    float s = fmaf(r2v[pt], acc[ct][pt][reg], c2a[reg]);
                    unsigned pb = (__float_as_uint(s) & 0xFFFFFC00u) |
                                  (unsigned)(kb0 + reg);
                    float u  = __uint_as_float(pb);
                    float t3 = __builtin_amdgcn_fmed3f(m2[pt], m3[pt], u);
                    float t2 = __builtin_amdgcn_fmed3f(m1[pt], m2[pt], u);
                    m1[pt] = fminf(m1[pt], u); m2[pt] = t2; m3[pt] = t3;
                }
            }
        }
    }

    // ---- merge chains across the 4 quad-lanes (butterfly: all lanes get it) --
    #pragma unroll
    for (int d = 16; d <= 32; d <<= 1) {
        #pragma unroll
        for (int pt = 0; pt < 2; ++pt) {
            float o1 = __shfl_xor(m1[pt], d), o2 = __shfl_xor(m2[pt], d),
                  o3 = __shfl_xor(m3[pt], d);
            float u, t2, t3;
            u = o1; t3 = __builtin_amdgcn_fmed3f(m2[pt], m3[pt], u);
            t2 = __builtin_amdgcn_fmed3f(m1[pt], m2[pt], u);
            m1[pt] = fminf(m1[pt], u); m2[pt] = t2; m3[pt] = t3;
            u = o2; t3 = __builtin_amdgcn_fmed3f(m2[pt], m3[pt], u);
            t2 = __builtin_amdgcn_fmed3f(m1[pt], m2[pt], u);
            m1[pt] = fminf(m1[pt], u); m2[pt] = t2; m3[pt] = t3;
            u = o3; t3 = __builtin_amdgcn_fmed3f(m2[pt], m3[pt], u);
            t2 = __builtin_amdgcn_fmed3f(m1[pt], m2[pt], u);
            m1[pt] = fminf(m1[pt], u); m2[pt] = t2; m3[pt] = t3;
        }
    }

    // ---- every wave: exact fp32 rescore of its own 32 positions + loss ----
    {
        float lsum = 0.f;
        #pragma unroll
        for (int pt = 0; pt < 2; ++pt) {
            int ks[3] = {(int)(__float_as_uint(m1[pt]) & 1023u),
                         (int)(__float_as_uint(m2[pt]) & 1023u),
                         (int)(__float_as_uint(m3[pt]) & 1023u)};

            // re-read this position's 32 channels (L2/L3-hot)
            float xr[32];
            const float* xgp = x + b * CHW + s0 + pt * 16 + lp;
            #pragma unroll
            for (int cs = 0; cs < 4; ++cs)
                #pragma unroll
                for (int j = 0; j < 8; ++j)
                    xr[cs * 8 + j] = xgp[(32 * cs + 8 * q + j) * HW];

            // exact fp32 rescore of the 3 candidates (same order as R4-R9)
            float dots[3];
            #pragma unroll
            for (int jj = 0; jj < 3; ++jj) {
                const float* crow = cb + ks[jj] * C_DIM + 8 * q;
                float p = 0.f;
                #pragma unroll
                for (int cs = 0; cs < 4; ++cs) {
                    float4 a0 = *(const float4*)(crow + 32 * cs);
                    float4 a1 = *(const float4*)(crow + 32 * cs + 4);
                    p = fmaf(xr[cs*8+0], a0.x, p); p = fmaf(xr[cs*8+1], a0.y, p);
                    p = fmaf(xr[cs*8+2], a0.z, p); p = fmaf(xr[cs*8+3], a0.w, p);
                    p = fmaf(xr[cs*8+4], a1.x, p); p = fmaf(xr[cs*8+5], a1.y, p);
                    p = fmaf(xr[cs*8+6], a1.z, p); p = fmaf(xr[cs*8+7], a1.w, p);
                }
                p += __shfl_xor(p, 16);
                p += __shfl_xor(p, 32);
                dots[jj] = p;
            }
            float sb = fmaf(r2v[pt], dots[0], c2w[ks[0]]); int kb = ks[0];
            float s2 = fmaf(r2v[pt], dots[1], c2w[ks[1]]);
            if (s2 < sb || (s2 == sb && ks[1] < kb)) { sb = s2; kb = ks[1]; }
            float s3 = fmaf(r2v[pt], dots[2], c2w[ks[2]]);
            if (s3 < sb || (s3 == sb && ks[2] < kb)) { sb = s3; kb = ks[2]; }

            if (ln < 16) idxw[bid * 128 + (w << 5) + pt * 16 + lp] = kb;
            lsum += sqrtf(fmaxf(1.0f + sb, 0.f));   // z2 == 1 after normalize
        }
        // each position counted by its 4 q-lanes -> scale 0.25
        #pragma unroll
        for (int off = 32; off > 0; off >>= 1) lsum += __shfl_down(lsum, off);
        if (ln == 0) atomicAdd(Sw, 0.25f * lsum);
    }
}

// ---------------------------------------------------------------------------
// Kernel 3: scatter q = codebook[idx] + finalize losses.
// thread = (position, channel-quad): ONE float4 gather from the code row
// (16B transaction) + 4 wave-coalesced scalar stores (fixed c, consecutive
// s -> 256B segments). 8192 blocks x 256.
// ---------------------------------------------------------------------------
__global__ void write_q(const float* __restrict__ cb,
                        const int* __restrict__ idxw,
                        const float* __restrict__ ws,
                        float* __restrict__ out) {
    int id = blockIdx.x * 256 + threadIdx.x;   // 2,097,152 = N_POS * 32
    int p  = id & (N_POS - 1);                 // position (lanes consecutive)
    int c4 = id >> 16;                         // channel quad 0..31
    int b  = p >> 12, s = p & 4095;
    int row = idxw[p];                         // coalesced 4B reads
    float4 v = ((const float4*)cb)[row * 32 + c4];   // 16B gather, L2-hot
    float* o = out + b * CHW + (c4 * 4) * HW + s;
    o[0]      = v.x;                           // each store: 64 lanes x 4B
    o[HW]     = v.y;                           //  = coalesced 256B segment
    o[2 * HW] = v.z;
    o[3 * HW] = v.w;
    if (id == 0) {                             // fold in loss finalize
        float S = *(const float*)((const char*)ws + WS_S);
        float m = S / (float)N_POS;
        out[Q_ELEMS]     = 0.25f * m;
        out[Q_ELEMS + 1] = m;
    }
}

extern "C" void kernel_launch(void* const* d_in, const int* in_sizes, int n_in,
                              void* d_out, int out_size, void* d_ws, size_t ws_size,
                              hipStream_t stream) {
    const float* x  = (const float*)d_in[0];   // [16,128,64,64]
    const float* cb = (const float*)d_in[1];   // [1024,128]
    float* out = (float*)d_out;
    float* ws  = (float*)d_ws;

    const float* c2w = (const float*)((const char*)d_ws + WS_C2);
    int*  idxw = (int*)((char*)d_ws + WS_IDX);
    float* Sw  = (float*)((char*)d_ws + WS_S);
    unsigned short* cbbf = (unsigned short*)d_out;   // scratch in d_out

    prep_kernel<<<K_CODES, 64, 0, stream>>>(cb, ws, cbbf);
    vq_mfma    <<<512, 256, 0, stream>>>(x, cb, cbbf, c2w, idxw, Sw);
    write_q    <<<Q_ELEMS / 1024, 256, 0, stream>>>(cb, idxw, ws, out);
}

// Round 5
// 80.967 us; speedup vs baseline: 1.6166x; 1.6166x over previous
//
#include <hip/hip_runtime.h>
#include <math.h>

// Problem constants
#define K_CODES 1024
#define C_DIM   128
#define HW      4096          // 64*64
#define CHW     (C_DIM*HW)    // per-batch stride in x
#define N_POS   65536         // 16*64*64
#define Q_ELEMS 8388608       // 16*128*64*64

// ws layout (byte offsets). Total < 272 KB (proven safe rounds 1-6).
#define WS_S    0             // float: sum of sqrt(d2min)
#define WS_C2   256           // float[1024]: ||c_k||^2
#define WS_IDX  8192          // int[65536]: final argmin index per position
                              // idxw[p] == argmin for (batch p>>12, spatial p&4095)

// d_out scratch (overwritten by write_q later; stream-ordered, safe):
//   offset 0: bf16 codebook, row k at k*256B, granule-col j holds channels of
//   granule (j ^ (k&7))  -> linear global_load_lds staging + conflict-free
//   swizzled ds_read_b128 A-frags.

typedef __attribute__((ext_vector_type(8))) short short8;   // 8 bf16 (4 VGPRs)
typedef __attribute__((ext_vector_type(4))) float f32x4;    // MFMA acc

__device__ __forceinline__ unsigned short f2bf(float f) {   // fp32 -> bf16 RNE
    unsigned u = __float_as_uint(f);
    u += 0x7FFFu + ((u >> 16) & 1u);
    return (unsigned short)(u >> 16);
}

// async global->LDS, 16B per lane; LDS dst = wave-uniform base + lane*16
__device__ __forceinline__ void gll16(const void* g, void* l) {
    __builtin_amdgcn_global_load_lds(
        (const __attribute__((address_space(1))) void*)g,
        (__attribute__((address_space(3))) void*)l, 16, 0, 0);
}

// ---------------------------------------------------------------------------
// Kernel 1: prep. Block k (64 lanes): row norm (same math as rounds 1-6),
// bf16 conversion into the COLUMN-SWIZZLED global layout, S zeroing.
// ---------------------------------------------------------------------------
__global__ void prep_kernel(const float* __restrict__ cb, float* __restrict__ ws,
                            unsigned short* __restrict__ cbbf) {
    __shared__ __align__(16) unsigned short srow[128];
    int k = blockIdx.x;
    int l = threadIdx.x;                       // 64 lanes = 1 wave
    if (k == 0 && l == 0) *(float*)((char*)ws + WS_S) = 0.f;
    float v1 = cb[k * C_DIM + l];
    float v2 = cb[k * C_DIM + 64 + l];
    int c1 = l, c2 = 64 + l;
    srow[(((c1 >> 3) ^ (k & 7)) << 3) | (c1 & 7)] = f2bf(v1);
    srow[(((c2 >> 3) ^ (k & 7)) << 3) | (c2 & 7)] = f2bf(v2);
    float ss = v1 * v1 + v2 * v2;
    #pragma unroll
    for (int off = 32; off > 0; off >>= 1) ss += __shfl_down(ss, off);
    if (l == 0) ((float*)((char*)ws + WS_C2))[k] = ss;
    __syncthreads();
    if (l < 16) ((uint4*)cbbf)[k * 16 + l] = ((const uint4*)srow)[l];
}

// ---------------------------------------------------------------------------
// Kernel 2: fused VQ. R11 = EXACT R6 (proven 61 us, absmax 0.0) + ONE change:
// kh=0 threads stash their phase-1 fp32 x values in LDS (xstash[c][66-pad])
// and the rescore phase reads the stash instead of re-issuing 64 strided
// global scalar loads per thread. Same thread writes & reads its own slots
// -> no barrier needed, bit-identical values. LDS 33.8 -> 67.3 KB = R7's
// footprint class (measured neutral vs R6 -> occupancy risk pre-cleared).
// Everything else byte-identical to R6: 1024 blocks x 256 thr, wave (pg,kh),
// single-buffered 16 KB chunks via global_load_lds, swizzled ds_read_b128,
// top-3 min+2x med3 with idx in low 10 bits, kh=1 publishes via mbuf, kh=0
// merges + exact fp32 rescore + loss.
// ---------------------------------------------------------------------------
__global__ __launch_bounds__(256, 2) void vq_mfma(const float* __restrict__ x,
                                                  const float* __restrict__ cb,
                                                  const unsigned short* __restrict__ cbbf,
                                                  const float* __restrict__ c2w,
                                                  int* __restrict__ idxw,
                                                  float* __restrict__ Sw) {
    __shared__ __align__(16) unsigned short cbuf[2 * 1024 * 8];  // 32 KB
    __shared__ float mbuf[2][2][16][3];                          // 768 B
    __shared__ float xstash[128][66];                            // 33 KB, 2-way free

    const int t  = threadIdx.x;
    const int w  = t >> 6;                      // wave 0..3
    const int kh = w & 1;                       // code half
    const int pg = w >> 1;                      // position group (32 pos)
    const int ln = t & 63;
    const int lp = ln & 15;                     // position lane (n index)
    const int q  = ln >> 4;                     // quad 0..3 (k sub-range)
    const int bid = blockIdx.x;
    const int b   = bid >> 6;                   // batch (64 blocks per image)
    const int s0  = (bid & 63) << 6;            // 64-position tile start

    // ---- x: bf16 B-frags (2 pos-tiles) + per-position norms ----
    short8 xf[2][4];
    float  r2v[2];
    {
        float ss[2] = {0.f, 0.f};
        #pragma unroll
        for (int pt = 0; pt < 2; ++pt) {
            const float* xgp = x + b * CHW + s0 + pg * 32 + pt * 16 + lp;
            const int pos = pg * 32 + pt * 16 + lp;   // 0..63 within block
            #pragma unroll
            for (int cs = 0; cs < 4; ++cs) {
                union { short8 v; unsigned short u[8]; } fu;
                #pragma unroll
                for (int j = 0; j < 8; ++j) {
                    float vv = xgp[(32 * cs + 8 * q + j) * HW];
                    ss[pt] = fmaf(vv, vv, ss[pt]);
                    fu.u[j] = f2bf(vv);
                    if (kh == 0) xstash[32 * cs + 8 * q + j][pos] = vv;
                }
                xf[pt][cs] = fu.v;
            }
        }
        #pragma unroll
        for (int pt = 0; pt < 2; ++pt) {
            float s = ss[pt];
            s += __shfl_xor(s, 16);
            s += __shfl_xor(s, 32);
            r2v[pt] = -2.0f / fmaxf(sqrtf(s), 1e-12f);  // F.normalize eps
        }
    }

    const float FMAX = __uint_as_float(0x7F7FFFFFu);
    float m1[2] = {FMAX, FMAX}, m2[2] = {FMAX, FMAX}, m3[2] = {FMAX, FMAX};

    // staging bases: per-lane global addr, wave-uniform LDS base
    const char* gbase = (const char*)cbbf + (kh * 512) * 256 + (pg * 512 + ln) * 16;
    char* lbase = (char*)cbuf + (kh * 1024 + pg * 512) * 16;

    #pragma unroll
    for (int r = 0; r < 8; ++r)                  // stage chunk 0
        gll16(gbase + r * 1024, lbase + r * 1024);
    __syncthreads();

    for (int i = 0; i < 8; ++i) {
        const int k0 = kh * 512 + i * 64;

        f32x4 acc[4][2];
        #pragma unroll
        for (int ct = 0; ct < 4; ++ct)
            #pragma unroll
            for (int pt = 0; pt < 2; ++pt) acc[ct][pt] = 0;

        const unsigned short* cbp = cbuf + kh * 8192;
        #pragma unroll
        for (int cs = 0; cs < 4; ++cs) {
            short8 ah[4];
            #pragma unroll
            for (int ct = 0; ct < 4; ++ct) {     // A[m=16ct+lp][k=32cs+8q+j]
                int g = (16 * ct + lp) * 16 + ((4 * cs + q) ^ (lp & 7));
                ah[ct] = *(const short8*)(cbp + g * 8);
            }
            #pragma unroll
            for (int ct = 0; ct < 4; ++ct)
                #pragma unroll
                for (int pt = 0; pt < 2; ++pt)
                    acc[ct][pt] = __builtin_amdgcn_mfma_f32_16x16x32_bf16(
                        ah[ct], xf[pt][cs], acc[ct][pt], 0, 0, 0);
        }

        // ---- epilogue: 32 scores, ~5 VALU each (fmaf, and_or, 2 med3, min) --
        #pragma unroll
        for (int ct = 0; ct < 4; ++ct) {
            float4 c2vv = *(const float4*)(c2w + k0 + 16 * ct + 4 * q);
            float c2a[4] = {c2vv.x, c2vv.y, c2vv.z, c2vv.w};
            const int kb0 = k0 + 16 * ct + 4 * q;
            #pragma unroll
            for (int pt = 0; pt < 2; ++pt) {
                #pragma unroll
                for (int reg = 0; reg < 4; ++reg) {
                    float s = fmaf(r2v[pt], acc[ct][pt][reg], c2a[reg]);
                    unsigned pb = (__float_as_uint(s) & 0xFFFFFC00u) |
                                  (unsigned)(kb0 + reg);
                    float u  = __uint_as_float(pb);
                    float t3 = __builtin_amdgcn_fmed3f(m2[pt], m3[pt], u);
                    float t2 = __builtin_amdgcn_fmed3f(m1[pt], m2[pt], u);
                    m1[pt] = fminf(m1[pt], u); m2[pt] = t2; m3[pt] = t3;
                }
            }
        }

        if (i < 7) {
            __syncthreads();                     // all reads of buffer done
            #pragma unroll
            for (int r = 0; r < 8; ++r)
                gll16(gbase + (i + 1) * 16384 + r * 1024, lbase + r * 1024);
            __syncthreads();                     // loads landed (vmcnt drain)
        }
    }

    // ---- merge chains across the 4 quad-lanes (butterfly: all lanes get it) --
    #pragma unroll
    for (int d = 16; d <= 32; d <<= 1) {
        #pragma unroll
        for (int pt = 0; pt < 2; ++pt) {
            float o1 = __shfl_xor(m1[pt], d), o2 = __shfl_xor(m2[pt], d),
                  o3 = __shfl_xor(m3[pt], d);
            float u, t2, t3;
            u = o1; t3 = __builtin_amdgcn_fmed3f(m2[pt], m3[pt], u);
            t2 = __builtin_amdgcn_fmed3f(m1[pt], m2[pt], u);
            m1[pt] = fminf(m1[pt], u); m2[pt] = t2; m3[pt] = t3;
            u = o2; t3 = __builtin_amdgcn_fmed3f(m2[pt], m3[pt], u);
            t2 = __builtin_amdgcn_fmed3f(m1[pt], m2[pt], u);
            m1[pt] = fminf(m1[pt], u); m2[pt] = t2; m3[pt] = t3;
            u = o3; t3 = __builtin_amdgcn_fmed3f(m2[pt], m3[pt], u);
            t2 = __builtin_amdgcn_fmed3f(m1[pt], m2[pt], u);
            m1[pt] = fminf(m1[pt], u); m2[pt] = t2; m3[pt] = t3;
        }
    }

    if (kh == 1 && ln < 16) {
        #pragma unroll
        for (int pt = 0; pt < 2; ++pt) {
            mbuf[pg][pt][lp][0] = m1[pt];
            mbuf[pg][pt][lp][1] = m2[pt];
            mbuf[pg][pt][lp][2] = m3[pt];
        }
    }
    __syncthreads();

    if (kh == 0) {
        float lsum = 0.f;
        #pragma unroll
        for (int pt = 0; pt < 2; ++pt) {
            // merge the kh=1 half's chain (broadcast LDS reads)
            #pragma unroll
            for (int c = 0; c < 3; ++c) {
                float u  = mbuf[pg][pt][lp][c];
                float t3 = __builtin_amdgcn_fmed3f(m2[pt], m3[pt], u);
                float t2 = __builtin_amdgcn_fmed3f(m1[pt], m2[pt], u);
                m1[pt] = fminf(m1[pt], u); m2[pt] = t2; m3[pt] = t3;
            }
            int ks[3] = {(int)(__float_as_uint(m1[pt]) & 1023u),
                         (int)(__float_as_uint(m2[pt]) & 1023u),
                         (int)(__float_as_uint(m3[pt]) & 1023u)};

            // this position's 32 channels: read back from the LDS stash
            // (same thread wrote these exact values in phase 1)
            float xr[32];
            const int pos = pg * 32 + pt * 16 + lp;
            #pragma unroll
            for (int cs = 0; cs < 4; ++cs)
                #pragma unroll
                for (int j = 0; j < 8; ++j)
                    xr[cs * 8 + j] = xstash[32 * cs + 8 * q + j][pos];

            // exact fp32 rescore of the 3 candidates (same order as R4-R6)
            float dots[3];
            #pragma unroll
            for (int jj = 0; jj < 3; ++jj) {
                const float* crow = cb + ks[jj] * C_DIM + 8 * q;
                float p = 0.f;
                #pragma unroll
                for (int cs = 0; cs < 4; ++cs) {
                    float4 a0 = *(const float4*)(crow + 32 * cs);
                    float4 a1 = *(const float4*)(crow + 32 * cs + 4);
                    p = fmaf(xr[cs*8+0], a0.x, p); p = fmaf(xr[cs*8+1], a0.y, p);
                    p = fmaf(xr[cs*8+2], a0.z, p); p = fmaf(xr[cs*8+3], a0.w, p);
                    p = fmaf(xr[cs*8+4], a1.x, p); p = fmaf(xr[cs*8+5], a1.y, p);
                    p = fmaf(xr[cs*8+6], a1.z, p); p = fmaf(xr[cs*8+7], a1.w, p);
                }
                p += __shfl_xor(p, 16);
                p += __shfl_xor(p, 32);
                dots[jj] = p;
            }
            float sb = fmaf(r2v[pt], dots[0], c2w[ks[0]]); int kb = ks[0];
            float s2 = fmaf(r2v[pt], dots[1], c2w[ks[1]]);
            if (s2 < sb || (s2 == sb && ks[1] < kb)) { sb = s2; kb = ks[1]; }
            float s3 = fmaf(r2v[pt], dots[2], c2w[ks[2]]);
            if (s3 < sb || (s3 == sb && ks[2] < kb)) { sb = s3; kb = ks[2]; }

            if (ln < 16) idxw[bid * 64 + pg * 32 + pt * 16 + lp] = kb;
            lsum += sqrtf(fmaxf(1.0f + sb, 0.f));   // z2 == 1 after normalize
        }
        // each position counted by its 4 q-lanes -> scale 0.25
        #pragma unroll
        for (int off = 32; off > 0; off >>= 1) lsum += __shfl_down(lsum, off);
        if (ln == 0) atomicAdd(Sw, 0.25f * lsum);
    }
}

// ---------------------------------------------------------------------------
// Kernel 3: scatter q = codebook[idx] + finalize losses.
// thread = (position, channel-quad): ONE float4 gather from the code row
// (16B transaction) + 4 wave-coalesced scalar stores (fixed c, consecutive
// s -> 256B segments). 8192 blocks x 256.
// ---------------------------------------------------------------------------
__global__ void write_q(const float* __restrict__ cb,
                        const int* __restrict__ idxw,
                        const float* __restrict__ ws,
                        float* __restrict__ out) {
    int id = blockIdx.x * 256 + threadIdx.x;   // 2,097,152 = N_POS * 32
    int p  = id & (N_POS - 1);                 // position (lanes consecutive)
    int c4 = id >> 16;                         // channel quad 0..31
    int b  = p >> 12, s = p & 4095;
    int row = idxw[p];                         // coalesced 4B reads
    float4 v = ((const float4*)cb)[row * 32 + c4];   // 16B gather, L2-hot
    float* o = out + b * CHW + (c4 * 4) * HW + s;
    o[0]      = v.x;                           // each store: 64 lanes x 4B
    o[HW]     = v.y;                           //  = coalesced 256B segment
    o[2 * HW] = v.z;
    o[3 * HW] = v.w;
    if (id == 0) {                             // fold in loss finalize
        float S = *(const float*)((const char*)ws + WS_S);
        float m = S / (float)N_POS;
        out[Q_ELEMS]     = 0.25f * m;
        out[Q_ELEMS + 1] = m;
    }
}

extern "C" void kernel_launch(void* const* d_in, const int* in_sizes, int n_in,
                              void* d_out, int out_size, void* d_ws, size_t ws_size,
                              hipStream_t stream) {
    const float* x  = (const float*)d_in[0];   // [16,128,64,64]
    const float* cb = (const float*)d_in[1];   // [1024,128]
    float* out = (float*)d_out;
    float* ws  = (float*)d_ws;

    const float* c2w = (const float*)((const char*)d_ws + WS_C2);
    int*  idxw = (int*)((char*)d_ws + WS_IDX);
    float* Sw  = (float*)((char*)d_ws + WS_S);
    unsigned short* cbbf = (unsigned short*)d_out;   // scratch in d_out

    prep_kernel<<<K_CODES, 64, 0, stream>>>(cb, ws, cbbf);
    vq_mfma    <<<N_POS / 64, 256, 0, stream>>>(x, cb, cbbf, c2w, idxw, Sw);
    write_q    <<<Q_ELEMS / 1024, 256, 0, stream>>>(cb, idxw, ws, out);
}

// Round 6
// 70.659 us; speedup vs baseline: 1.8524x; 1.1459x over previous
//
#include <hip/hip_runtime.h>
#include <math.h>

// Problem constants
#define K_CODES 1024
#define C_DIM   128
#define HW      4096          // 64*64
#define CHW     (C_DIM*HW)    // per-batch stride in x
#define N_POS   65536         // 16*64*64
#define Q_ELEMS 8388608       // 16*128*64*64

// ws layout (byte offsets). Total < 272 KB (proven safe rounds 1-6).
#define WS_S    0             // float: sum of sqrt(d2min)
#define WS_C2   256           // float[1024]: ||c_k||^2
#define WS_IDX  8192          // int[65536]: final argmin index per position
                              // idxw[p] == argmin for (batch p>>12, spatial p&4095)

// d_out scratch (overwritten later; stream-ordered, safe):
//   offset 0: bf16 codebook (256 KB), row k at k*256B, granule-col j holds
//   channels of granule (j ^ (k&7)) -> linear global_load_lds staging +
//   conflict-free swizzled ds_read_b128 A-frags. This region == q's
//   (b=0, c<16) slice, so b=0 blocks do NOT fuse their q-store (write_q0
//   covers batch 0 after vq completes).

typedef __attribute__((ext_vector_type(8))) short short8;   // 8 bf16 (4 VGPRs)
typedef __attribute__((ext_vector_type(4))) float f32x4;    // MFMA acc

__device__ __forceinline__ unsigned short f2bf(float f) {   // fp32 -> bf16 RNE
    unsigned u = __float_as_uint(f);
    u += 0x7FFFu + ((u >> 16) & 1u);
    return (unsigned short)(u >> 16);
}

// async global->LDS, 16B per lane; LDS dst = wave-uniform base + lane*16
__device__ __forceinline__ void gll16(const void* g, void* l) {
    __builtin_amdgcn_global_load_lds(
        (const __attribute__((address_space(1))) void*)g,
        (__attribute__((address_space(3))) void*)l, 16, 0, 0);
}

// ---------------------------------------------------------------------------
// Kernel 1: prep. Block k (64 lanes): row norm (same math as rounds 1-6),
// bf16 conversion into the COLUMN-SWIZZLED global layout, S zeroing.
// ---------------------------------------------------------------------------
__global__ void prep_kernel(const float* __restrict__ cb, float* __restrict__ ws,
                            unsigned short* __restrict__ cbbf) {
    __shared__ __align__(16) unsigned short srow[128];
    int k = blockIdx.x;
    int l = threadIdx.x;                       // 64 lanes = 1 wave
    if (k == 0 && l == 0) *(float*)((char*)ws + WS_S) = 0.f;
    float v1 = cb[k * C_DIM + l];
    float v2 = cb[k * C_DIM + 64 + l];
    int c1 = l, c2 = 64 + l;
    srow[(((c1 >> 3) ^ (k & 7)) << 3) | (c1 & 7)] = f2bf(v1);
    srow[(((c2 >> 3) ^ (k & 7)) << 3) | (c2 & 7)] = f2bf(v2);
    float ss = v1 * v1 + v2 * v2;
    #pragma unroll
    for (int off = 32; off > 0; off >>= 1) ss += __shfl_down(ss, off);
    if (l == 0) ((float*)((char*)ws + WS_C2))[k] = ss;
    __syncthreads();
    if (l < 16) ((uint4*)cbbf)[k * 16 + l] = ((const uint4*)srow)[l];
}

// ---------------------------------------------------------------------------
// Kernel 2: fused VQ. R12 = EXACT R6 scan (proven 61 us, absmax 0.0) + FUSED
// q-STORE TAIL: after the rescore, the block's 64 indices are published to
// LDS (ibuf) and all 4 waves cooperatively gather cb rows (8 float4/thread,
// L2-hot) and write q with 256B-coalesced stores -- the same access pattern
// write_q used, but overlapped with other blocks' scan phases (every pipe
// <31% busy, HBM 96% idle). b=0 blocks skip the store (their c<16 region is
// the live cbbf scratch); write_q0 covers batch 0 afterwards. All math,
// ordering, tie-breaks, and the loss path are byte-identical to R6.
// ---------------------------------------------------------------------------
__global__ __launch_bounds__(256, 2) void vq_mfma(const float* __restrict__ x,
                                                  const float* __restrict__ cb,
                                                  const unsigned short* __restrict__ cbbf,
                                                  const float* __restrict__ c2w,
                                                  int* __restrict__ idxw,
                                                  float* __restrict__ Sw,
                                                  float* __restrict__ out) {
    __shared__ __align__(16) unsigned short cbuf[2 * 1024 * 8];  // 32 KB
    __shared__ float mbuf[2][2][16][3];                          // 768 B
    __shared__ int ibuf[64];                                     // 256 B

    const int t  = threadIdx.x;
    const int w  = t >> 6;                      // wave 0..3
    const int kh = w & 1;                       // code half
    const int pg = w >> 1;                      // position group (32 pos)
    const int ln = t & 63;
    const int lp = ln & 15;                     // position lane (n index)
    const int q  = ln >> 4;                     // quad 0..3 (k sub-range)
    const int bid = blockIdx.x;
    const int b   = bid >> 6;                   // batch (64 blocks per image)
    const int s0  = (bid & 63) << 6;            // 64-position tile start

    // ---- x: bf16 B-frags (2 pos-tiles) + per-position norms ----
    short8 xf[2][4];
    float  r2v[2];
    {
        float ss[2] = {0.f, 0.f};
        #pragma unroll
        for (int pt = 0; pt < 2; ++pt) {
            const float* xgp = x + b * CHW + s0 + pg * 32 + pt * 16 + lp;
            #pragma unroll
            for (int cs = 0; cs < 4; ++cs) {
                union { short8 v; unsigned short u[8]; } fu;
                #pragma unroll
                for (int j = 0; j < 8; ++j) {
                    float vv = xgp[(32 * cs + 8 * q + j) * HW];
                    ss[pt] = fmaf(vv, vv, ss[pt]);
                    fu.u[j] = f2bf(vv);
                }
                xf[pt][cs] = fu.v;
            }
        }
        #pragma unroll
        for (int pt = 0; pt < 2; ++pt) {
            float s = ss[pt];
            s += __shfl_xor(s, 16);
            s += __shfl_xor(s, 32);
            r2v[pt] = -2.0f / fmaxf(sqrtf(s), 1e-12f);  // F.normalize eps
        }
    }

    const float FMAX = __uint_as_float(0x7F7FFFFFu);
    float m1[2] = {FMAX, FMAX}, m2[2] = {FMAX, FMAX}, m3[2] = {FMAX, FMAX};

    // staging bases: per-lane global addr, wave-uniform LDS base
    const char* gbase = (const char*)cbbf + (kh * 512) * 256 + (pg * 512 + ln) * 16;
    char* lbase = (char*)cbuf + (kh * 1024 + pg * 512) * 16;

    #pragma unroll
    for (int r = 0; r < 8; ++r)                  // stage chunk 0
        gll16(gbase + r * 1024, lbase + r * 1024);
    __syncthreads();

    for (int i = 0; i < 8; ++i) {
        const int k0 = kh * 512 + i * 64;

        f32x4 acc[4][2];
        #pragma unroll
        for (int ct = 0; ct < 4; ++ct)
            #pragma unroll
            for (int pt = 0; pt < 2; ++pt) acc[ct][pt] = 0;

        const unsigned short* cbp = cbuf + kh * 8192;
        #pragma unroll
        for (int cs = 0; cs < 4; ++cs) {
            short8 ah[4];
            #pragma unroll
            for (int ct = 0; ct < 4; ++ct) {     // A[m=16ct+lp][k=32cs+8q+j]
                int g = (16 * ct + lp) * 16 + ((4 * cs + q) ^ (lp & 7));
                ah[ct] = *(const short8*)(cbp + g * 8);
            }
            #pragma unroll
            for (int ct = 0; ct < 4; ++ct)
                #pragma unroll
                for (int pt = 0; pt < 2; ++pt)
                    acc[ct][pt] = __builtin_amdgcn_mfma_f32_16x16x32_bf16(
                        ah[ct], xf[pt][cs], acc[ct][pt], 0, 0, 0);
        }

        // ---- epilogue: 32 scores, ~5 VALU each (fmaf, and_or, 2 med3, min) --
        #pragma unroll
        for (int ct = 0; ct < 4; ++ct) {
            float4 c2vv = *(const float4*)(c2w + k0 + 16 * ct + 4 * q);
            float c2a[4] = {c2vv.x, c2vv.y, c2vv.z, c2vv.w};
            const int kb0 = k0 + 16 * ct + 4 * q;
            #pragma unroll
            for (int pt = 0; pt < 2; ++pt) {
                #pragma unroll
                for (int reg = 0; reg < 4; ++reg) {
                    float s = fmaf(r2v[pt], acc[ct][pt][reg], c2a[reg]);
                    unsigned pb = (__float_as_uint(s) & 0xFFFFFC00u) |
                                  (unsigned)(kb0 + reg);
                    float u  = __uint_as_float(pb);
                    float t3 = __builtin_amdgcn_fmed3f(m2[pt], m3[pt], u);
                    float t2 = __builtin_amdgcn_fmed3f(m1[pt], m2[pt], u);
                    m1[pt] = fminf(m1[pt], u); m2[pt] = t2; m3[pt] = t3;
                }
            }
        }

        if (i < 7) {
            __syncthreads();                     // all reads of buffer done
            #pragma unroll
            for (int r = 0; r < 8; ++r)
                gll16(gbase + (i + 1) * 16384 + r * 1024, lbase + r * 1024);
            __syncthreads();                     // loads landed (vmcnt drain)
        }
    }

    // ---- merge chains across the 4 quad-lanes (butterfly: all lanes get it) --
    #pragma unroll
    for (int d = 16; d <= 32; d <<= 1) {
        #pragma unroll
        for (int pt = 0; pt < 2; ++pt) {
            float o1 = __shfl_xor(m1[pt], d), o2 = __shfl_xor(m2[pt], d),
                  o3 = __shfl_xor(m3[pt], d);
            float u, t2, t3;
            u = o1; t3 = __builtin_amdgcn_fmed3f(m2[pt], m3[pt], u);
            t2 = __builtin_amdgcn_fmed3f(m1[pt], m2[pt], u);
            m1[pt] = fminf(m1[pt], u); m2[pt] = t2; m3[pt] = t3;
            u = o2; t3 = __builtin_amdgcn_fmed3f(m2[pt], m3[pt], u);
            t2 = __builtin_amdgcn_fmed3f(m1[pt], m2[pt], u);
            m1[pt] = fminf(m1[pt], u); m2[pt] = t2; m3[pt] = t3;
            u = o3; t3 = __builtin_amdgcn_fmed3f(m2[pt], m3[pt], u);
            t2 = __builtin_amdgcn_fmed3f(m1[pt], m2[pt], u);
            m1[pt] = fminf(m1[pt], u); m2[pt] = t2; m3[pt] = t3;
        }
    }

    if (kh == 1 && ln < 16) {
        #pragma unroll
        for (int pt = 0; pt < 2; ++pt) {
            mbuf[pg][pt][lp][0] = m1[pt];
            mbuf[pg][pt][lp][1] = m2[pt];
            mbuf[pg][pt][lp][2] = m3[pt];
        }
    }
    __syncthreads();

    if (kh == 0) {
        float lsum = 0.f;
        #pragma unroll
        for (int pt = 0; pt < 2; ++pt) {
            // merge the kh=1 half's chain (broadcast LDS reads)
            #pragma unroll
            for (int c = 0; c < 3; ++c) {
                float u  = mbuf[pg][pt][lp][c];
                float t3 = __builtin_amdgcn_fmed3f(m2[pt], m3[pt], u);
                float t2 = __builtin_amdgcn_fmed3f(m1[pt], m2[pt], u);
                m1[pt] = fminf(m1[pt], u); m2[pt] = t2; m3[pt] = t3;
            }
            int ks[3] = {(int)(__float_as_uint(m1[pt]) & 1023u),
                         (int)(__float_as_uint(m2[pt]) & 1023u),
                         (int)(__float_as_uint(m3[pt]) & 1023u)};

            // re-read this position's 32 channels (L1/L2-hot)
            float xr[32];
            const float* xgp = x + b * CHW + s0 + pg * 32 + pt * 16 + lp;
            #pragma unroll
            for (int cs = 0; cs < 4; ++cs)
                #pragma unroll
                for (int j = 0; j < 8; ++j)
                    xr[cs * 8 + j] = xgp[(32 * cs + 8 * q + j) * HW];

            // exact fp32 rescore of the 3 candidates (same order as R4-R6)
            float dots[3];
            #pragma unroll
            for (int jj = 0; jj < 3; ++jj) {
                const float* crow = cb + ks[jj] * C_DIM + 8 * q;
                float p = 0.f;
                #pragma unroll
                for (int cs = 0; cs < 4; ++cs) {
                    float4 a0 = *(const float4*)(crow + 32 * cs);
                    float4 a1 = *(const float4*)(crow + 32 * cs + 4);
                    p = fmaf(xr[cs*8+0], a0.x, p); p = fmaf(xr[cs*8+1], a0.y, p);
                    p = fmaf(xr[cs*8+2], a0.z, p); p = fmaf(xr[cs*8+3], a0.w, p);
                    p = fmaf(xr[cs*8+4], a1.x, p); p = fmaf(xr[cs*8+5], a1.y, p);
                    p = fmaf(xr[cs*8+6], a1.z, p); p = fmaf(xr[cs*8+7], a1.w, p);
                }
                p += __shfl_xor(p, 16);
                p += __shfl_xor(p, 32);
                dots[jj] = p;
            }
            float sb = fmaf(r2v[pt], dots[0], c2w[ks[0]]); int kb = ks[0];
            float s2 = fmaf(r2v[pt], dots[1], c2w[ks[1]]);
            if (s2 < sb || (s2 == sb && ks[1] < kb)) { sb = s2; kb = ks[1]; }
            float s3 = fmaf(r2v[pt], dots[2], c2w[ks[2]]);
            if (s3 < sb || (s3 == sb && ks[2] < kb)) { sb = s3; kb = ks[2]; }

            if (ln < 16) {
                idxw[bid * 64 + pg * 32 + pt * 16 + lp] = kb;
                ibuf[pg * 32 + pt * 16 + lp] = kb;   // publish for fused store
            }
            lsum += sqrtf(fmaxf(1.0f + sb, 0.f));   // z2 == 1 after normalize
        }
        // each position counted by its 4 q-lanes -> scale 0.25
        #pragma unroll
        for (int off = 32; off > 0; off >>= 1) lsum += __shfl_down(lsum, off);
        if (ln == 0) atomicAdd(Sw, 0.25f * lsum);
    }

    // ---- fused q-store (b>0; batch 0's region aliases cbbf -> write_q0) ----
    __syncthreads();                             // ibuf visible to all waves
    if (b != 0) {
        const int row = ibuf[ln];                // position s0+ln's code
        const float4* cbr = (const float4*)cb + row * 32;
        float* ob = out + b * CHW + s0 + ln;
        #pragma unroll
        for (int c4 = w * 8; c4 < w * 8 + 8; ++c4) {   // wave w: 32 channels
            float4 v = cbr[c4];                  // 16B gather, L2-hot
            float* o = ob + (c4 * 4) * HW;
            o[0]      = v.x;                     // each store: 64 lanes x 4B
            o[HW]     = v.y;                     //  = coalesced 256B segment
            o[2 * HW] = v.z;
            o[3 * HW] = v.w;
        }
    }
}

// ---------------------------------------------------------------------------
// Kernel 3: batch-0 scatter (region was cbbf scratch during vq) + losses.
// 512 blocks x 256 thr: id -> (spatial s<4096, channel-quad c4<32); same
// float4-gather + coalesced-store pattern as the old write_q, b=0 only.
// ---------------------------------------------------------------------------
__global__ void write_q0(const float* __restrict__ cb,
                         const int* __restrict__ idxw,
                         const float* __restrict__ ws,
                         float* __restrict__ out) {
    int id = blockIdx.x * 256 + threadIdx.x;   // 131072 = 4096 * 32
    int s  = id & 4095;                        // spatial (lanes consecutive)
    int c4 = id >> 12;                         // channel quad 0..31
    int row = idxw[s];                         // batch 0 -> p == s
    float4 v = ((const float4*)cb)[row * 32 + c4];   // 16B gather, L2-hot
    float* o = out + (c4 * 4) * HW + s;        // b = 0
    o[0]      = v.x;
    o[HW]     = v.y;
    o[2 * HW] = v.z;
    o[3 * HW] = v.w;
    if (id == 0) {                             // loss finalize (after vq)
        float S = *(const float*)((const char*)ws + WS_S);
        float m = S / (float)N_POS;
        out[Q_ELEMS]     = 0.25f * m;
        out[Q_ELEMS + 1] = m;
    }
}

extern "C" void kernel_launch(void* const* d_in, const int* in_sizes, int n_in,
                              void* d_out, int out_size, void* d_ws, size_t ws_size,
                              hipStream_t stream) {
    const float* x  = (const float*)d_in[0];   // [16,128,64,64]
    const float* cb = (const float*)d_in[1];   // [1024,128]
    float* out = (float*)d_out;
    float* ws  = (float*)d_ws;

    const float* c2w = (const float*)((const char*)d_ws + WS_C2);
    int*  idxw = (int*)((char*)d_ws + WS_IDX);
    float* Sw  = (float*)((char*)d_ws + WS_S);
    unsigned short* cbbf = (unsigned short*)d_out;   // scratch in d_out

    prep_kernel<<<K_CODES, 64, 0, stream>>>(cb, ws, cbbf);
    vq_mfma    <<<N_POS / 64, 256, 0, stream>>>(x, cb, cbbf, c2w, idxw, Sw, out);
    write_q0   <<<512, 256, 0, stream>>>(cb, idxw, ws, out);
}

// Round 7
// 68.359 us; speedup vs baseline: 1.9147x; 1.0336x over previous
//
#include <hip/hip_runtime.h>
#include <math.h>

// Problem constants
#define K_CODES 1024
#define C_DIM   128
#define HW      4096          // 64*64
#define CHW     (C_DIM*HW)    // per-batch stride in x
#define N_POS   65536         // 16*64*64
#define Q_ELEMS 8388608       // 16*128*64*64

// ws layout (byte offsets).
#define WS_S    0             // float: sum of sqrt(d2min)
#define WS_C2   256           // float[1024]: ||c_k||^2
#define WS_IDX  8192          // int[65536]: final argmin index per position

// d_out scratch (overwritten later; stream-ordered, safe):
//   offset 0: bf16 codebook (256 KB), row k at k*256B, granule-col j holds
//   channels of granule (j ^ (k&7)) -> linear global_load_lds staging +
//   conflict-free swizzled ds_read_b128 A-frags. This region == q's
//   (b=0, c<16) slice, so b=0 blocks skip the fused q-store (write_q0
//   covers batch 0 after vq completes).

typedef __attribute__((ext_vector_type(8))) short short8;   // 8 bf16 (4 VGPRs)
typedef __attribute__((ext_vector_type(4))) float f32x4;    // MFMA acc

__device__ __forceinline__ unsigned short f2bf(float f) {   // fp32 -> bf16 RNE
    unsigned u = __float_as_uint(f);
    u += 0x7FFFu + ((u >> 16) & 1u);
    return (unsigned short)(u >> 16);
}

// async global->LDS, 16B per lane; LDS dst = wave-uniform base (+lane*16 by HW)
__device__ __forceinline__ void gll16(const void* g, void* l) {
    __builtin_amdgcn_global_load_lds(
        (const __attribute__((address_space(1))) void*)g,
        (__attribute__((address_space(3))) void*)l, 16, 0, 0);
}

// ---------------------------------------------------------------------------
// Kernel 1: prep. Block k (64 lanes): row norm, bf16 conversion into the
// COLUMN-SWIZZLED global layout, S zeroing. (unchanged)
// ---------------------------------------------------------------------------
__global__ void prep_kernel(const float* __restrict__ cb, float* __restrict__ ws,
                            unsigned short* __restrict__ cbbf) {
    __shared__ __align__(16) unsigned short srow[128];
    int k = blockIdx.x;
    int l = threadIdx.x;                       // 64 lanes = 1 wave
    if (k == 0 && l == 0) *(float*)((char*)ws + WS_S) = 0.f;
    float v1 = cb[k * C_DIM + l];
    float v2 = cb[k * C_DIM + 64 + l];
    int c1 = l, c2 = 64 + l;
    srow[(((c1 >> 3) ^ (k & 7)) << 3) | (c1 & 7)] = f2bf(v1);
    srow[(((c2 >> 3) ^ (k & 7)) << 3) | (c2 & 7)] = f2bf(v2);
    float ss = v1 * v1 + v2 * v2;
    #pragma unroll
    for (int off = 32; off > 0; off >>= 1) ss += __shfl_down(ss, off);
    if (l == 0) ((float*)((char*)ws + WS_C2))[k] = ss;
    __syncthreads();
    if (l < 16) ((uint4*)cbbf)[k * 16 + l] = ((const uint4*)srow)[l];
}

// ---------------------------------------------------------------------------
// Kernel 2: fused VQ. R13 restructure: WAVE-PRIVATE STAGING, BARRIER-FREE SCAN.
// 1024 blocks x 256 thr (4 waves), block = 64 positions (unchanged). NEW wave
// decomposition: wave w owns code-quarter [w*256,(w+1)*256) for ALL 64
// positions (xf[4 pt]). Each 8 KB chunk (32 codes) is staged into the wave's
// PRIVATE LDS region (double-buffered) and read by that wave only:
//   - ds_read traffic + bank conflicts HALVE (chunk read once, not twice)
//   - sync is wave-local s_waitcnt vmcnt(0) -> ZERO barriers in the scan
//     (16 -> 0); waves free-run and destagger so pipes overlap.
// Bit-exactness vs R6/R12: same MFMA operands & accumulation order, same
// per-chain insert order (ct asc, reg asc), packed (score|idx) strict total
// order -> unique global top-3 regardless of merge topology; rescore waves
// 0/1 cover positions 0-31/32-63 with R6's exact per-atomic partials and
// reduction trees. Fused q-store tail kept from R12 (b>0).
// ---------------------------------------------------------------------------
__global__ __launch_bounds__(256, 2) void vq_mfma(const float* __restrict__ x,
                                                  const float* __restrict__ cb,
                                                  const unsigned short* __restrict__ cbbf,
                                                  const float* __restrict__ c2w,
                                                  int* __restrict__ idxw,
                                                  float* __restrict__ Sw,
                                                  float* __restrict__ out) {
    __shared__ __align__(16) unsigned short cbuf[2][4][4096]; // 2 x 4 x 8 KB
    __shared__ float mbuf[4][4][16][3];                       // 3 KB
    __shared__ int ibuf[64];                                  // 256 B

    const int t  = threadIdx.x;
    const int w  = t >> 6;                      // wave 0..3 = code quarter
    const int ln = t & 63;
    const int lp = ln & 15;                     // position lane (n index)
    const int q  = ln >> 4;                     // quad 0..3 (k sub-range)
    const int bid = blockIdx.x;
    const int b   = bid >> 6;                   // batch (64 blocks per image)
    const int s0  = (bid & 63) << 6;            // 64-position tile start

    // wave's quarter of the pre-swizzled bf16 codebook (64 KB)
    const char* gq = (const char*)cbbf + (w << 16);

    { // stage chunk 0 -> buf 0 NOW; latency hides under the x-phase
        const char* gs = gq + (ln << 4);
        char* ld = (char*)&cbuf[0][w][0];
        #pragma unroll
        for (int r = 0; r < 8; ++r) gll16(gs + r * 1024, ld + r * 1024);
    }

    // ---- x: bf16 B-frags (4 pos-tiles = all 64 positions) + norms ----
    short8 xf[4][4];
    float  r2v[4];
    {
        float ss[4];
        #pragma unroll
        for (int pt = 0; pt < 4; ++pt) {
            ss[pt] = 0.f;
            const float* xgp = x + b * CHW + s0 + pt * 16 + lp;
            #pragma unroll
            for (int cs = 0; cs < 4; ++cs) {
                union { short8 v; unsigned short u[8]; } fu;
                #pragma unroll
                for (int j = 0; j < 8; ++j) {
                    float vv = xgp[(32 * cs + 8 * q + j) * HW];
                    ss[pt] = fmaf(vv, vv, ss[pt]);
                    fu.u[j] = f2bf(vv);
                }
                xf[pt][cs] = fu.v;
            }
        }
        #pragma unroll
        for (int pt = 0; pt < 4; ++pt) {
            float s = ss[pt];
            s += __shfl_xor(s, 16);
            s += __shfl_xor(s, 32);
            r2v[pt] = -2.0f / fmaxf(sqrtf(s), 1e-12f);  // F.normalize eps
        }
    }

    const float FMAX = __uint_as_float(0x7F7FFFFFu);
    float m1[4] = {FMAX, FMAX, FMAX, FMAX};
    float m2[4] = {FMAX, FMAX, FMAX, FMAX};
    float m3[4] = {FMAX, FMAX, FMAX, FMAX};

    // chunk 0 landed (wave-local; also drains x loads, long consumed)
    asm volatile("s_waitcnt vmcnt(0)" ::: "memory");
    __builtin_amdgcn_sched_barrier(0);

    for (int i = 0; i < 8; ++i) {               // 8 chunks x 32 codes
        if (i < 7) {                             // stage next chunk (private)
            asm volatile("s_waitcnt lgkmcnt(0)" ::: "memory");
            const char* gs = gq + (i + 1) * 8192 + (ln << 4);
            char* ld = (char*)&cbuf[(i + 1) & 1][w][0];
            #pragma unroll
            for (int r = 0; r < 8; ++r) gll16(gs + r * 1024, ld + r * 1024);
        }

        const int k0 = (w << 8) + (i << 5);
        const unsigned short* cbp = &cbuf[i & 1][w][0];

        f32x4 acc[2][4];
        #pragma unroll
        for (int ct = 0; ct < 2; ++ct)
            #pragma unroll
            for (int pt = 0; pt < 4; ++pt) acc[ct][pt] = 0;

        #pragma unroll
        for (int cs = 0; cs < 4; ++cs) {
            short8 ah[2];
            #pragma unroll
            for (int ct = 0; ct < 2; ++ct) {     // A[m=16ct+lp][k=32cs+8q+j]
                int g = (16 * ct + lp) * 16 + ((4 * cs + q) ^ (lp & 7));
                ah[ct] = *(const short8*)(cbp + g * 8);
            }
            #pragma unroll
            for (int ct = 0; ct < 2; ++ct)
                #pragma unroll
                for (int pt = 0; pt < 4; ++pt)
                    acc[ct][pt] = __builtin_amdgcn_mfma_f32_16x16x32_bf16(
                        ah[ct], xf[pt][cs], acc[ct][pt], 0, 0, 0);
        }

        // ---- epilogue: 32 scores/lane (2ct x 4pt x 4reg) ----
        #pragma unroll
        for (int ct = 0; ct < 2; ++ct) {
            float4 c2vv = *(const float4*)(c2w + k0 + 16 * ct + 4 * q);
            float c2a[4] = {c2vv.x, c2vv.y, c2vv.z, c2vv.w};
            const int kb0 = k0 + 16 * ct + 4 * q;
            #pragma unroll
            for (int pt = 0; pt < 4; ++pt) {
                #pragma unroll
                for (int reg = 0; reg < 4; ++reg) {
                    float s = fmaf(r2v[pt], acc[ct][pt][reg], c2a[reg]);
                    unsigned pb = (__float_as_uint(s) & 0xFFFFFC00u) |
                                  (unsigned)(kb0 + reg);
                    float u  = __uint_as_float(pb);
                    float t3 = __builtin_amdgcn_fmed3f(m2[pt], m3[pt], u);
                    float t2 = __builtin_amdgcn_fmed3f(m1[pt], m2[pt], u);
                    m1[pt] = fminf(m1[pt], u); m2[pt] = t2; m3[pt] = t3;
                }
            }
        }

        if (i < 7) {                             // next chunk landed (wave-local)
            asm volatile("s_waitcnt vmcnt(0)" ::: "memory");
            __builtin_amdgcn_sched_barrier(0);
        }
    }

    // ---- merge chains across the 4 quad-lanes (butterfly, all 4 pt) ----
    #pragma unroll
    for (int d = 16; d <= 32; d <<= 1) {
        #pragma unroll
        for (int pt = 0; pt < 4; ++pt) {
            float o1 = __shfl_xor(m1[pt], d), o2 = __shfl_xor(m2[pt], d),
                  o3 = __shfl_xor(m3[pt], d);
            float u, t2, t3;
            u = o1; t3 = __builtin_amdgcn_fmed3f(m2[pt], m3[pt], u);
            t2 = __builtin_amdgcn_fmed3f(m1[pt], m2[pt], u);
            m1[pt] = fminf(m1[pt], u); m2[pt] = t2; m3[pt] = t3;
            u = o2; t3 = __builtin_amdgcn_fmed3f(m2[pt], m3[pt], u);
            t2 = __builtin_amdgcn_fmed3f(m1[pt], m2[pt], u);
            m1[pt] = fminf(m1[pt], u); m2[pt] = t2; m3[pt] = t3;
            u = o3; t3 = __builtin_amdgcn_fmed3f(m2[pt], m3[pt], u);
            t2 = __builtin_amdgcn_fmed3f(m1[pt], m2[pt], u);
            m1[pt] = fminf(m1[pt], u); m2[pt] = t2; m3[pt] = t3;
        }
    }

    // publish all 4 per-quarter chains
    if (ln < 16) {
        #pragma unroll
        for (int pt = 0; pt < 4; ++pt) {
            mbuf[w][pt][lp][0] = m1[pt];
            mbuf[w][pt][lp][1] = m2[pt];
            mbuf[w][pt][lp][2] = m3[pt];
        }
    }
    __syncthreads();

    // ---- rescore: wave 0 -> positions 0-31 (pt 0,1), wave 1 -> 32-63 ----
    if (w < 2) {
        float lsum = 0.f;
        #pragma unroll
        for (int ptl = 0; ptl < 2; ++ptl) {
            const int pt = 2 * w + ptl;
            // merge the 4 quarters' chains (fixed order; unique top-3 set)
            float M1 = FMAX, M2 = FMAX, M3 = FMAX;
            #pragma unroll
            for (int ww = 0; ww < 4; ++ww)
                #pragma unroll
                for (int c = 0; c < 3; ++c) {
                    float u  = mbuf[ww][pt][lp][c];
                    float t3 = __builtin_amdgcn_fmed3f(M2, M3, u);
                    float t2 = __builtin_amdgcn_fmed3f(M1, M2, u);
                    M1 = fminf(M1, u); M2 = t2; M3 = t3;
                }
            int ks[3] = {(int)(__float_as_uint(M1) & 1023u),
                         (int)(__float_as_uint(M2) & 1023u),
                         (int)(__float_as_uint(M3) & 1023u)};

            // re-read this position's 32 channels (L1/L2-hot)
            float xr[32];
            const float* xgp = x + b * CHW + s0 + pt * 16 + lp;
            #pragma unroll
            for (int cs = 0; cs < 4; ++cs)
                #pragma unroll
                for (int j = 0; j < 8; ++j)
                    xr[cs * 8 + j] = xgp[(32 * cs + 8 * q + j) * HW];

            // exact fp32 rescore of the 3 candidates (same order as R4-R12)
            float dots[3];
            #pragma unroll
            for (int jj = 0; jj < 3; ++jj) {
                const float* crow = cb + ks[jj] * C_DIM + 8 * q;
                float p = 0.f;
                #pragma unroll
                for (int cs = 0; cs < 4; ++cs) {
                    float4 a0 = *(const float4*)(crow + 32 * cs);
                    float4 a1 = *(const float4*)(crow + 32 * cs + 4);
                    p = fmaf(xr[cs*8+0], a0.x, p); p = fmaf(xr[cs*8+1], a0.y, p);
                    p = fmaf(xr[cs*8+2], a0.z, p); p = fmaf(xr[cs*8+3], a0.w, p);
                    p = fmaf(xr[cs*8+4], a1.x, p); p = fmaf(xr[cs*8+5], a1.y, p);
                    p = fmaf(xr[cs*8+6], a1.z, p); p = fmaf(xr[cs*8+7], a1.w, p);
                }
                p += __shfl_xor(p, 16);
                p += __shfl_xor(p, 32);
                dots[jj] = p;
            }
            float sb = fmaf(r2v[pt], dots[0], c2w[ks[0]]); int kb = ks[0];
            float s2 = fmaf(r2v[pt], dots[1], c2w[ks[1]]);
            if (s2 < sb || (s2 == sb && ks[1] < kb)) { sb = s2; kb = ks[1]; }
            float s3 = fmaf(r2v[pt], dots[2], c2w[ks[2]]);
            if (s3 < sb || (s3 == sb && ks[2] < kb)) { sb = s3; kb = ks[2]; }

            if (ln < 16) {
                idxw[bid * 64 + pt * 16 + lp] = kb;
                ibuf[pt * 16 + lp] = kb;         // publish for fused store
            }
            lsum += sqrtf(fmaxf(1.0f + sb, 0.f));   // z2 == 1 after normalize
        }
        // each position counted by its 4 q-lanes -> scale 0.25
        #pragma unroll
        for (int off = 32; off > 0; off >>= 1) lsum += __shfl_down(lsum, off);
        if (ln == 0) atomicAdd(Sw, 0.25f * lsum);
    }

    // ---- fused q-store (b>0; batch 0's region aliases cbbf -> write_q0) ----
    __syncthreads();                             // ibuf visible to all waves
    if (b != 0) {
        const int row = ibuf[ln];                // position s0+ln's code
        const float4* cbr = (const float4*)cb + row * 32;
        float* ob = out + b * CHW + s0 + ln;
        #pragma unroll
        for (int c4 = w * 8; c4 < w * 8 + 8; ++c4) {   // wave w: 32 channels
            float4 v = cbr[c4];                  // 16B gather, L2-hot
            float* o = ob + (c4 * 4) * HW;
            o[0]      = v.x;                     // each store: 64 lanes x 4B
            o[HW]     = v.y;                     //  = coalesced 256B segment
            o[2 * HW] = v.z;
            o[3 * HW] = v.w;
        }
    }
}

// ---------------------------------------------------------------------------
// Kernel 3: batch-0 scatter (region was cbbf scratch during vq) + losses.
// ---------------------------------------------------------------------------
__global__ void write_q0(const float* __restrict__ cb,
                         const int* __restrict__ idxw,
                         const float* __restrict__ ws,
                         float* __restrict__ out) {
    int id = blockIdx.x * 256 + threadIdx.x;   // 131072 = 4096 * 32
    int s  = id & 4095;                        // spatial (lanes consecutive)
    int c4 = id >> 12;                         // channel quad 0..31
    int row = idxw[s];                         // batch 0 -> p == s
    float4 v = ((const float4*)cb)[row * 32 + c4];   // 16B gather, L2-hot
    float* o = out + (c4 * 4) * HW + s;        // b = 0
    o[0]      = v.x;
    o[HW]     = v.y;
    o[2 * HW] = v.z;
    o[3 * HW] = v.w;
    if (id == 0) {                             // loss finalize (after vq)
        float S = *(const float*)((const char*)ws + WS_S);
        float m = S / (float)N_POS;
        out[Q_ELEMS]     = 0.25f * m;
        out[Q_ELEMS + 1] = m;
    }
}

extern "C" void kernel_launch(void* const* d_in, const int* in_sizes, int n_in,
                              void* d_out, int out_size, void* d_ws, size_t ws_size,
                              hipStream_t stream) {
    const float* x  = (const float*)d_in[0];   // [16,128,64,64]
    const float* cb = (const float*)d_in[1];   // [1024,128]
    float* out = (float*)d_out;
    float* ws  = (float*)d_ws;

    const float* c2w = (const float*)((const char*)d_ws + WS_C2);
    int*  idxw = (int*)((char*)d_ws + WS_IDX);
    float* Sw  = (float*)((char*)d_ws + WS_S);
    unsigned short* cbbf = (unsigned short*)d_out;   // scratch in d_out

    prep_kernel<<<K_CODES, 64, 0, stream>>>(cb, ws, cbbf);
    vq_mfma    <<<N_POS / 64, 256, 0, stream>>>(x, cb, cbbf, c2w, idxw, Sw, out);
    write_q0   <<<512, 256, 0, stream>>>(cb, idxw, ws, out);
}